// Round 3
// baseline (6780.231 us; speedup 1.0000x reference)
//
#include <hip/hip_runtime.h>
#include <stdint.h>

#define NN 50000   // nodes
#define NE 600000  // edges
#define NG 1000    // graphs
#define AD 64      // input feat
#define HD 128     // hidden
#define OD 256     // output
#define BN_EPS_F 1e-5f

typedef __attribute__((ext_vector_type(8))) short  mbf16x8;
typedef __attribute__((ext_vector_type(4))) float  mf32x4;
typedef __attribute__((ext_vector_type(4))) unsigned short mu16x4;
typedef __attribute__((ext_vector_type(2))) unsigned short mu16x2;
typedef __attribute__((ext_vector_type(4))) unsigned int   mu32x4;

__device__ __forceinline__ float bf2f(unsigned short u) {
    union { unsigned int i; float f; } v; v.i = ((unsigned int)u) << 16; return v.f;
}
__device__ __forceinline__ float bf2f_lo(unsigned int u) {
    union { unsigned int i; float f; } v; v.i = u << 16; return v.f;
}
__device__ __forceinline__ float bf2f_hi(unsigned int u) {
    union { unsigned int i; float f; } v; v.i = u & 0xffff0000u; return v.f;
}
__device__ __forceinline__ unsigned short f2bf(float f) {
    union { float f; unsigned int i; } v; v.f = f;
    unsigned int r = v.i + 0x7fffu + ((v.i >> 16) & 1u);  // RNE
    return (unsigned short)(r >> 16);
}

// ---------------------------------------------------------------------------
// GEMM: y_bf16[N,128] = in[N,K] @ W_f32[K,128] + bias_f32  (bf16 MFMA, fp32 acc)
// block = 256 threads (4 waves), tile = 64 rows x 128 cols
// ---------------------------------------------------------------------------
template <int K, bool IN_BF16>
__global__ __launch_bounds__(256) void gemm_kernel(
    const void* __restrict__ in, const float* __restrict__ W,
    const float* __restrict__ bias, unsigned short* __restrict__ out,
    int n_rows)
{
    constexpr int SA = K + 8;  // padded LDS row stride (bf16 elems)
    constexpr int SB = K + 8;
    __shared__ unsigned short zs[64 * SA];   // A tile (bf16)
    __shared__ unsigned short ws[128 * SB];  // W^T: ws[n][k] (bf16)

    const int tid = threadIdx.x;
    const int wave = tid >> 6, lane = tid & 63;
    const int row0 = blockIdx.x * 64;

    // ---- stage A tile -> LDS (convert to bf16) ----
    if constexpr (IN_BF16) {
        const unsigned short* src = (const unsigned short*)in;
        constexpr int LPR = K / 8;  // 16B loads per row
        for (int i = tid; i < 64 * LPR; i += 256) {
            int r = i / LPR, c8 = (i % LPR) * 8;
            mu32x4 v = {0, 0, 0, 0};
            if (row0 + r < n_rows)
                v = *(const mu32x4*)(src + (size_t)(row0 + r) * K + c8);
            *(mu32x4*)(&zs[r * SA + c8]) = v;
        }
    } else {
        const float* src = (const float*)in;
        constexpr int LPR = K / 4;  // float4 loads per row
        for (int i = tid; i < 64 * LPR; i += 256) {
            int r = i / LPR, c4 = (i % LPR) * 4;
            mf32x4 v = {0.f, 0.f, 0.f, 0.f};
            if (row0 + r < n_rows)
                v = *(const mf32x4*)(src + (size_t)(row0 + r) * K + c4);
            mu16x4 o;
            o[0] = f2bf(v[0]); o[1] = f2bf(v[1]); o[2] = f2bf(v[2]); o[3] = f2bf(v[3]);
            *(mu16x4*)(&zs[r * SA + c4]) = o;
        }
    }
    // ---- stage W^T -> LDS (fp32 -> bf16) ----
    for (int i = tid; i < K * 128 / 4; i += 256) {
        const int base = i * 4;
        const int k = base >> 7, n = base & 127;
        mf32x4 v = *(const mf32x4*)(W + base);
        ws[(n + 0) * SB + k] = f2bf(v[0]);
        ws[(n + 1) * SB + k] = f2bf(v[1]);
        ws[(n + 2) * SB + k] = f2bf(v[2]);
        ws[(n + 3) * SB + k] = f2bf(v[3]);
    }
    __syncthreads();

    // ---- MFMA: wave handles rows [wave*16, +16), 8 col-tiles of 16 ----
    mf32x4 acc[8];
#pragma unroll
    for (int t = 0; t < 8; t++) acc[t] = {0.f, 0.f, 0.f, 0.f};
    const int m = wave * 16 + (lane & 15);
    const int kq = (lane >> 4) * 8;
#pragma unroll
    for (int kk = 0; kk < K / 32; kk++) {
        const int k0 = kk * 32 + kq;
        mbf16x8 a = *(const mbf16x8*)(&zs[m * SA + k0]);
#pragma unroll
        for (int t = 0; t < 8; t++) {
            const int n = t * 16 + (lane & 15);
            mbf16x8 b = *(const mbf16x8*)(&ws[n * SB + k0]);
            acc[t] = __builtin_amdgcn_mfma_f32_16x16x32_bf16(a, b, acc[t], 0, 0, 0);
        }
    }
    // ---- epilogue: +bias, store bf16. D layout: col=lane&15, row=quad*4+reg
    const int rbase = wave * 16 + ((lane >> 4) << 2);
#pragma unroll
    for (int t = 0; t < 8; t++) {
        const int c = t * 16 + (lane & 15);
        const float bv = bias[c];
#pragma unroll
        for (int r = 0; r < 4; r++) {
            const int grow = row0 + rbase + r;
            if (grow < n_rows)
                out[(size_t)grow * 128 + c] = f2bf(acc[t][r] + bv);
        }
    }
}

// ---------------------------------------------------------------------------
// z = (1+eps[l]) * h   (bf16 -> fp32), 8 elems/thread
// ---------------------------------------------------------------------------
__global__ __launch_bounds__(256) void zinit_kernel(
    const unsigned short* __restrict__ h, const float* __restrict__ eps,
    int l, float* __restrict__ z)
{
    const float e = 1.0f + eps[l];
    const size_t base = ((size_t)blockIdx.x * 256 + threadIdx.x) * 8;
    if (base >= (size_t)NN * HD) return;
    mu32x4 v = *(const mu32x4*)(h + base);
    mf32x4 a, b;
    a[0] = e * bf2f_lo(v[0]); a[1] = e * bf2f_hi(v[0]);
    a[2] = e * bf2f_lo(v[1]); a[3] = e * bf2f_hi(v[1]);
    b[0] = e * bf2f_lo(v[2]); b[1] = e * bf2f_hi(v[2]);
    b[2] = e * bf2f_lo(v[3]); b[3] = e * bf2f_hi(v[3]);
    *(mf32x4*)(z + base) = a;
    *(mf32x4*)(z + base + 4) = b;
}

// ---------------------------------------------------------------------------
// scatter: z[row[e]] += h[col[e]]  (16 threads/edge x 8 cols, fp32 atomics)
// ---------------------------------------------------------------------------
__global__ __launch_bounds__(256) void scatter_kernel(
    const int* __restrict__ ei, const unsigned short* __restrict__ h,
    float* __restrict__ z)
{
    const int gid = blockIdx.x * 256 + threadIdx.x;
    const int e = gid >> 4, i = gid & 15;
    if (e >= NE) return;
    const int row = ei[e];
    const int col = ei[NE + e];
    if ((unsigned)row >= NN || (unsigned)col >= NN) return;  // defensive
    mu32x4 v = *(const mu32x4*)(h + (size_t)col * HD + i * 8);
    float* zp = z + (size_t)row * HD + i * 8;
    atomicAdd(zp + 0, bf2f_lo(v[0])); atomicAdd(zp + 1, bf2f_hi(v[0]));
    atomicAdd(zp + 2, bf2f_lo(v[1])); atomicAdd(zp + 3, bf2f_hi(v[1]));
    atomicAdd(zp + 4, bf2f_lo(v[2])); atomicAdd(zp + 5, bf2f_hi(v[2]));
    atomicAdd(zp + 6, bf2f_lo(v[3])); atomicAdd(zp + 7, bf2f_hi(v[3]));
}

// ---------------------------------------------------------------------------
// per-column sum / sumsq of y[N,128] -> stats[0..127]=sum, [128..255]=sumsq
// ---------------------------------------------------------------------------
__global__ __launch_bounds__(256) void stats_kernel(
    const unsigned short* __restrict__ y, float* __restrict__ stats, int n_rows)
{
    const int tid = threadIdx.x;
    const int c0 = (tid & 63) * 2;
    const int rg = tid >> 6;  // 0..3
    float s0 = 0.f, s1 = 0.f, q0 = 0.f, q1 = 0.f;
    for (int r = blockIdx.x * 4 + rg; r < n_rows; r += gridDim.x * 4) {
        mu16x2 v = *(const mu16x2*)(y + (size_t)r * 128 + c0);
        float a = bf2f(v[0]), b = bf2f(v[1]);
        if (!(fabsf(a) < 1e30f)) a = 0.f;   // guard NaN/inf
        if (!(fabsf(b) < 1e30f)) b = 0.f;
        s0 += a; q0 += a * a; s1 += b; q1 += b * b;
    }
    __shared__ float reds[4 * 128];
    __shared__ float redq[4 * 128];
    reds[rg * 128 + c0] = s0; reds[rg * 128 + c0 + 1] = s1;
    redq[rg * 128 + c0] = q0; redq[rg * 128 + c0 + 1] = q1;
    __syncthreads();
    if (tid < 128) {
        float s = reds[tid] + reds[128 + tid] + reds[256 + tid] + reds[384 + tid];
        float q = redq[tid] + redq[128 + tid] + redq[256 + tid] + redq[384 + tid];
        atomicAdd(&stats[tid], s);
        atomicAdd(&stats[128 + tid], q);
    }
}

// stats -> (scale, shift) per column
__global__ void finalize_kernel(
    const float* __restrict__ stats, const float* __restrict__ gamma,
    const float* __restrict__ beta, float* __restrict__ ss, float inv_n)
{
    const int c = threadIdx.x;
    const float mean = stats[c] * inv_n;
    float var = stats[128 + c] * inv_n - mean * mean;
    var = fmaxf(var, 0.0f);  // guard catastrophic cancellation
    const float inv = rsqrtf(var + BN_EPS_F);
    const float scale = gamma[c] * inv;
    ss[c] = scale;
    ss[128 + c] = beta[c] - mean * scale;
}

// out = relu(y*scale + shift), 8 elems/thread; OUT32: fp32 out else bf16
template <bool OUT32>
__global__ __launch_bounds__(256) void bnrelu_kernel(
    const unsigned short* __restrict__ y, const float* __restrict__ ss,
    void* __restrict__ outp)
{
    const size_t base = ((size_t)blockIdx.x * 256 + threadIdx.x) * 8;
    if (base >= (size_t)NN * HD) return;
    const int c = (int)(base & 127);
    mu32x4 v = *(const mu32x4*)(y + base);
    mf32x4 sc0 = *(const mf32x4*)(ss + c);
    mf32x4 sc1 = *(const mf32x4*)(ss + c + 4);
    mf32x4 sh0 = *(const mf32x4*)(ss + 128 + c);
    mf32x4 sh1 = *(const mf32x4*)(ss + 128 + c + 4);
    float r0 = fmaxf(bf2f_lo(v[0]) * sc0[0] + sh0[0], 0.f);
    float r1 = fmaxf(bf2f_hi(v[0]) * sc0[1] + sh0[1], 0.f);
    float r2 = fmaxf(bf2f_lo(v[1]) * sc0[2] + sh0[2], 0.f);
    float r3 = fmaxf(bf2f_hi(v[1]) * sc0[3] + sh0[3], 0.f);
    float r4 = fmaxf(bf2f_lo(v[2]) * sc1[0] + sh1[0], 0.f);
    float r5 = fmaxf(bf2f_hi(v[2]) * sc1[1] + sh1[1], 0.f);
    float r6 = fmaxf(bf2f_lo(v[3]) * sc1[2] + sh1[2], 0.f);
    float r7 = fmaxf(bf2f_hi(v[3]) * sc1[3] + sh1[3], 0.f);
    if constexpr (OUT32) {
        float* out = (float*)outp;
        mf32x4 a = {r0, r1, r2, r3}, b = {r4, r5, r6, r7};
        *(mf32x4*)(out + base) = a;
        *(mf32x4*)(out + base + 4) = b;
    } else {
        unsigned short* out = (unsigned short*)outp;
        mu16x4 oa, ob;
        oa[0] = f2bf(r0); oa[1] = f2bf(r1); oa[2] = f2bf(r2); oa[3] = f2bf(r3);
        ob[0] = f2bf(r4); ob[1] = f2bf(r5); ob[2] = f2bf(r6); ob[3] = f2bf(r7);
        *(mu16x4*)(out + base) = oa;
        *(mu16x4*)(out + base + 4) = ob;
    }
}

// graph start offsets from sorted batch_index: start[g] = first n with batch[n] >= g
__global__ void starts_kernel(const int* __restrict__ batch, int* __restrict__ start)
{
    const int n = blockIdx.x * blockDim.x + threadIdx.x;
    if (n >= NN) return;
    int b = batch[n];
    int pb = (n == 0) ? -1 : batch[n - 1];
    if (b > NG - 1) b = NG - 1;
    if (pb > NG - 1) pb = NG - 1;
    for (int g = pb + 1; g <= b; g++) start[g] = n;
    if (n == NN - 1)
        for (int g = b + 1; g <= NG; g++) start[g] = NN;
}

// pooled[g] = sum of h_f32 rows in [start[g], start[g+1])
__global__ __launch_bounds__(128) void pool_kernel(
    const float* __restrict__ h, const int* __restrict__ start,
    float* __restrict__ pooled)
{
    const int g = blockIdx.x, c = threadIdx.x;
    int s = start[g], e = start[g + 1];
    if (s < 0) s = 0;
    if (e > NN) e = NN;
    float acc = 0.f;
    for (int n = s; n < e; n++) acc += h[(size_t)n * 128 + c];
    pooled[(size_t)g * 128 + c] = acc;
}

// out[g][o] = pooled[g] . proj_W[:,o] + proj_b[o]   (all fp32)
__global__ __launch_bounds__(256) void final_kernel(
    const float* __restrict__ pooled, const float* __restrict__ pw,
    const float* __restrict__ pb, float* __restrict__ out)
{
    __shared__ float pl[128];
    const int g = blockIdx.x, o = threadIdx.x;
    if (o < 128) pl[o] = pooled[(size_t)g * 128 + o];
    __syncthreads();
    float acc = pb[o];
#pragma unroll 4
    for (int k = 0; k < 128; k++) acc += pl[k] * pw[k * 256 + o];
    out[(size_t)g * 256 + o] = acc;
}

// ---------------------------------------------------------------------------
extern "C" void kernel_launch(void* const* d_in, const int* in_sizes, int n_in,
                              void* d_out, int out_size, void* d_ws, size_t ws_size,
                              hipStream_t stream)
{
    const float* x      = (const float*)d_in[0];
    const int*   edge   = (const int*)d_in[1];
    const int*   batch  = (const int*)d_in[2];
    // d_in[3] = num_graphs scalar (G=1000, compile-time)
    const float* emb_W  = (const float*)d_in[4];
    const float* emb_b  = (const float*)d_in[5];
    const float* W1     = (const float*)d_in[6];
    const float* b1     = (const float*)d_in[7];
    const float* g1     = (const float*)d_in[8];
    const float* be1    = (const float*)d_in[9];
    const float* W2     = (const float*)d_in[10];
    const float* b2     = (const float*)d_in[11];
    const float* g2     = (const float*)d_in[12];
    const float* be2    = (const float*)d_in[13];
    const float* eps    = (const float*)d_in[14];
    const float* proj_W = (const float*)d_in[15];
    const float* proj_b = (const float*)d_in[16];
    float* out = (float*)d_out;

    // ---- workspace layout: small buffers first ----
    char* ws = (char*)d_ws;
    size_t off = 0;
    auto take = [&](size_t bytes) -> char* {
        char* p = ws + off;
        off += (bytes + 255) & ~(size_t)255;
        return p;
    };
    float*          stats  = (float*)take(6 * 2 * HD * 4);       // 6 KB
    float*          ss     = (float*)take(6 * 2 * HD * 4);       // 6 KB
    int*            start  = (int*)take((NG + 1) * 4);           // 4 KB
    float*          pooled = (float*)take((size_t)NG * HD * 4);  // 512 KB
    float*          z_f32  = (float*)take((size_t)NN * HD * 4);  // 25.6 MB
    unsigned short* h      = (unsigned short*)take((size_t)NN * HD * 2);  // 12.8 MB
    unsigned short* ybuf   = (unsigned short*)take((size_t)NN * HD * 2);  // 12.8 MB
    unsigned short* z2     = (unsigned short*)z_f32;  // alias: z_f32 dead when z2 live
    float*          hf     = z_f32;                   // alias: final-layer h (fp32)

    hipMemsetAsync(stats, 0, 6 * 2 * HD * 4, stream);

    const int gemm_grid = (NN + 63) / 64;       // 782
    const int ew_grid   = (NN * HD / 8) / 256;  // 3125
    const float inv_n = 1.0f / (float)NN;

    // embed: h = x @ emb_W + emb_b   (x fp32, K=64)
    gemm_kernel<AD, false><<<gemm_grid, 256, 0, stream>>>(x, emb_W, emb_b, h, NN);

    for (int l = 0; l < 3; l++) {
        zinit_kernel<<<ew_grid, 256, 0, stream>>>(h, eps, l, z_f32);
        scatter_kernel<<<NE * 16 / 256, 256, 0, stream>>>(edge, h, z_f32);
        gemm_kernel<HD, false><<<gemm_grid, 256, 0, stream>>>(
            z_f32, W1 + (size_t)l * HD * HD, b1 + l * HD, ybuf, NN);
        stats_kernel<<<256, 256, 0, stream>>>(ybuf, stats + (2 * l) * 256, NN);
        finalize_kernel<<<1, 128, 0, stream>>>(stats + (2 * l) * 256, g1 + l * HD,
                                               be1 + l * HD, ss + (2 * l) * 256, inv_n);
        bnrelu_kernel<false><<<ew_grid, 256, 0, stream>>>(ybuf, ss + (2 * l) * 256, z2);
        gemm_kernel<HD, true><<<gemm_grid, 256, 0, stream>>>(
            z2, W2 + (size_t)l * HD * HD, b2 + l * HD, ybuf, NN);
        stats_kernel<<<256, 256, 0, stream>>>(ybuf, stats + (2 * l + 1) * 256, NN);
        finalize_kernel<<<1, 128, 0, stream>>>(stats + (2 * l + 1) * 256, g2 + l * HD,
                                               be2 + l * HD, ss + (2 * l + 1) * 256, inv_n);
        if (l < 2)
            bnrelu_kernel<false><<<ew_grid, 256, 0, stream>>>(ybuf, ss + (2 * l + 1) * 256, h);
        else
            bnrelu_kernel<true><<<ew_grid, 256, 0, stream>>>(ybuf, ss + (2 * l + 1) * 256, hf);
    }

    starts_kernel<<<(NN + 255) / 256, 256, 0, stream>>>(batch, start);
    pool_kernel<<<NG, 128, 0, stream>>>(hf, start, pooled);
    final_kernel<<<NG, 256, 0, stream>>>(pooled, proj_W, proj_b, out);
}

// Round 4
// 867.028 us; speedup vs baseline: 7.8201x; 7.8201x over previous
//
#include <hip/hip_runtime.h>
#include <stdint.h>

#define NN 50000   // nodes
#define NE 600000  // edges
#define NG 1000    // graphs
#define AD 64      // input feat
#define HD 128     // hidden
#define OD 256     // output
#define BN_EPS_F 1e-5f

typedef __attribute__((ext_vector_type(8))) short  mbf16x8;
typedef __attribute__((ext_vector_type(4))) float  mf32x4;
typedef __attribute__((ext_vector_type(4))) unsigned short mu16x4;
typedef __attribute__((ext_vector_type(2))) unsigned short mu16x2;
typedef __attribute__((ext_vector_type(4))) unsigned int   mu32x4;

__device__ __forceinline__ float bf2f(unsigned short u) {
    union { unsigned int i; float f; } v; v.i = ((unsigned int)u) << 16; return v.f;
}
__device__ __forceinline__ float bf2f_lo(unsigned int u) {
    union { unsigned int i; float f; } v; v.i = u << 16; return v.f;
}
__device__ __forceinline__ float bf2f_hi(unsigned int u) {
    union { unsigned int i; float f; } v; v.i = u & 0xffff0000u; return v.f;
}
__device__ __forceinline__ unsigned short f2bf(float f) {
    union { float f; unsigned int i; } v; v.f = f;
    unsigned int r = v.i + 0x7fffu + ((v.i >> 16) & 1u);  // RNE
    return (unsigned short)(r >> 16);
}

// ---------------------------------------------------------------------------
// GEMM: y_bf16[N,128] = in[N,K] @ W_f32[K,128] + bias_f32  (bf16 MFMA, fp32 acc)
// block = 256 threads (4 waves), tile = 64 rows x 128 cols
// ---------------------------------------------------------------------------
template <int K, bool IN_BF16>
__global__ __launch_bounds__(256) void gemm_kernel(
    const void* __restrict__ in, const float* __restrict__ W,
    const float* __restrict__ bias, unsigned short* __restrict__ out,
    int n_rows)
{
    constexpr int SA = K + 8;  // padded LDS row stride (bf16 elems)
    constexpr int SB = K + 8;
    __shared__ unsigned short zs[64 * SA];   // A tile (bf16)
    __shared__ unsigned short ws[128 * SB];  // W^T: ws[n][k] (bf16)

    const int tid = threadIdx.x;
    const int wave = tid >> 6, lane = tid & 63;
    const int row0 = blockIdx.x * 64;

    // ---- stage A tile -> LDS (convert to bf16 if needed) ----
    if constexpr (IN_BF16) {
        const unsigned short* src = (const unsigned short*)in;
        constexpr int LPR = K / 8;  // 16B loads per row
        for (int i = tid; i < 64 * LPR; i += 256) {
            int r = i / LPR, c8 = (i % LPR) * 8;
            mu32x4 v = {0, 0, 0, 0};
            if (row0 + r < n_rows)
                v = *(const mu32x4*)(src + (size_t)(row0 + r) * K + c8);
            *(mu32x4*)(&zs[r * SA + c8]) = v;
        }
    } else {
        const float* src = (const float*)in;
        constexpr int LPR = K / 4;  // float4 loads per row
        for (int i = tid; i < 64 * LPR; i += 256) {
            int r = i / LPR, c4 = (i % LPR) * 4;
            mf32x4 v = {0.f, 0.f, 0.f, 0.f};
            if (row0 + r < n_rows)
                v = *(const mf32x4*)(src + (size_t)(row0 + r) * K + c4);
            mu16x4 o;
            o[0] = f2bf(v[0]); o[1] = f2bf(v[1]); o[2] = f2bf(v[2]); o[3] = f2bf(v[3]);
            *(mu16x4*)(&zs[r * SA + c4]) = o;
        }
    }
    // ---- stage W^T -> LDS (fp32 -> bf16) ----
    for (int i = tid; i < K * 128 / 4; i += 256) {
        const int base = i * 4;
        const int k = base >> 7, n = base & 127;
        mf32x4 v = *(const mf32x4*)(W + base);
        ws[(n + 0) * SB + k] = f2bf(v[0]);
        ws[(n + 1) * SB + k] = f2bf(v[1]);
        ws[(n + 2) * SB + k] = f2bf(v[2]);
        ws[(n + 3) * SB + k] = f2bf(v[3]);
    }
    __syncthreads();

    // ---- MFMA: wave handles rows [wave*16, +16), 8 col-tiles of 16 ----
    mf32x4 acc[8];
#pragma unroll
    for (int t = 0; t < 8; t++) acc[t] = {0.f, 0.f, 0.f, 0.f};
    const int m = wave * 16 + (lane & 15);
    const int kq = (lane >> 4) * 8;
#pragma unroll
    for (int kk = 0; kk < K / 32; kk++) {
        const int k0 = kk * 32 + kq;
        mbf16x8 a = *(const mbf16x8*)(&zs[m * SA + k0]);
#pragma unroll
        for (int t = 0; t < 8; t++) {
            const int n = t * 16 + (lane & 15);
            mbf16x8 b = *(const mbf16x8*)(&ws[n * SB + k0]);
            acc[t] = __builtin_amdgcn_mfma_f32_16x16x32_bf16(a, b, acc[t], 0, 0, 0);
        }
    }
    // ---- epilogue: +bias, store bf16. D layout: col=lane&15, row=quad*4+reg
    const int rbase = wave * 16 + ((lane >> 4) << 2);
#pragma unroll
    for (int t = 0; t < 8; t++) {
        const int c = t * 16 + (lane & 15);
        const float bv = bias[c];
#pragma unroll
        for (int r = 0; r < 4; r++) {
            const int grow = row0 + rbase + r;
            if (grow < n_rows)
                out[(size_t)grow * 128 + c] = f2bf(acc[t][r] + bv);
        }
    }
}

// ---------------------------------------------------------------------------
// CSR build: degree histogram -> exclusive scan -> fill adjacency
// ---------------------------------------------------------------------------
__global__ __launch_bounds__(256) void deg_kernel(
    const int* __restrict__ ei, int* __restrict__ cursor)
{
    const int e = blockIdx.x * 256 + threadIdx.x;
    if (e >= NE) return;
    const int row = ei[e];
    if ((unsigned)row < NN) atomicAdd(&cursor[row], 1);
}

// single block, 1024 threads: exclusive scan of cursor (=deg) -> rowptr, cursor
__global__ __launch_bounds__(1024) void scan_kernel(
    int* __restrict__ cursor, int* __restrict__ rowptr)
{
    __shared__ int partial[1024];
    const int t = threadIdx.x;
    constexpr int CH = (NN + 1023) / 1024;  // 49
    const int base = t * CH;
    int sum = 0;
    for (int i = 0; i < CH; i++) {
        const int idx = base + i;
        if (idx < NN) sum += cursor[idx];
    }
    partial[t] = sum;
    __syncthreads();
    // Hillis-Steele inclusive scan
    for (int ofs = 1; ofs < 1024; ofs <<= 1) {
        int v = (t >= ofs) ? partial[t - ofs] : 0;
        __syncthreads();
        partial[t] += v;
        __syncthreads();
    }
    int run = (t == 0) ? 0 : partial[t - 1];
    for (int i = 0; i < CH; i++) {
        const int idx = base + i;
        if (idx < NN) {
            const int d = cursor[idx];
            rowptr[idx] = run;
            cursor[idx] = run;  // fill cursor = start offsets
            run += d;
        }
    }
    if (t == 1023) rowptr[NN] = partial[1023];
}

__global__ __launch_bounds__(256) void fill_kernel(
    const int* __restrict__ ei, int* __restrict__ cursor, int* __restrict__ adj)
{
    const int e = blockIdx.x * 256 + threadIdx.x;
    if (e >= NE) return;
    const int row = ei[e];
    const int col = ei[NE + e];
    if ((unsigned)row >= NN || (unsigned)col >= NN) return;
    const int slot = atomicAdd(&cursor[row], 1);
    adj[slot] = col;
}

// ---------------------------------------------------------------------------
// gather: z[n] = (1+eps[l])*h[n] + sum_{c in adj[n]} h[c]   (bf16 out, fp32 acc)
// 2 nodes per 256-block; 128 threads per node (one per feature)
// ---------------------------------------------------------------------------
__global__ __launch_bounds__(256) void gather_kernel(
    const unsigned short* __restrict__ h, const int* __restrict__ rowptr,
    const int* __restrict__ adj, const float* __restrict__ eps, int l,
    unsigned short* __restrict__ z)
{
    const int node = blockIdx.x * 2 + (threadIdx.x >> 7);
    const int c = threadIdx.x & 127;
    if (node >= NN) return;
    const float e = 1.0f + eps[l];
    float acc = e * bf2f(h[(size_t)node * HD + c]);
    const int s = rowptr[node], t = rowptr[node + 1];
    int i = s;
    for (; i + 1 < t; i += 2) {  // 2-way unroll for load overlap
        const int c0 = adj[i], c1 = adj[i + 1];
        acc += bf2f(h[(size_t)c0 * HD + c]);
        acc += bf2f(h[(size_t)c1 * HD + c]);
    }
    if (i < t) acc += bf2f(h[(size_t)adj[i] * HD + c]);
    z[(size_t)node * HD + c] = f2bf(acc);
}

// ---------------------------------------------------------------------------
// per-column sum / sumsq of y[N,128] -> stats[0..127]=sum, [128..255]=sumsq
// ---------------------------------------------------------------------------
__global__ __launch_bounds__(256) void stats_kernel(
    const unsigned short* __restrict__ y, float* __restrict__ stats, int n_rows)
{
    const int tid = threadIdx.x;
    const int c0 = (tid & 63) * 2;
    const int rg = tid >> 6;  // 0..3
    float s0 = 0.f, s1 = 0.f, q0 = 0.f, q1 = 0.f;
    for (int r = blockIdx.x * 4 + rg; r < n_rows; r += gridDim.x * 4) {
        mu16x2 v = *(const mu16x2*)(y + (size_t)r * 128 + c0);
        float a = bf2f(v[0]), b = bf2f(v[1]);
        s0 += a; q0 += a * a; s1 += b; q1 += b * b;
    }
    __shared__ float reds[4 * 128];
    __shared__ float redq[4 * 128];
    reds[rg * 128 + c0] = s0; reds[rg * 128 + c0 + 1] = s1;
    redq[rg * 128 + c0] = q0; redq[rg * 128 + c0 + 1] = q1;
    __syncthreads();
    if (tid < 128) {
        float s = reds[tid] + reds[128 + tid] + reds[256 + tid] + reds[384 + tid];
        float q = redq[tid] + redq[128 + tid] + redq[256 + tid] + redq[384 + tid];
        atomicAdd(&stats[tid], s);
        atomicAdd(&stats[128 + tid], q);
    }
}

// stats -> (scale, shift) per column
__global__ void finalize_kernel(
    const float* __restrict__ stats, const float* __restrict__ gamma,
    const float* __restrict__ beta, float* __restrict__ ss, float inv_n)
{
    const int c = threadIdx.x;
    const float mean = stats[c] * inv_n;
    float var = stats[128 + c] * inv_n - mean * mean;
    var = fmaxf(var, 0.0f);
    const float inv = rsqrtf(var + BN_EPS_F);
    const float scale = gamma[c] * inv;
    ss[c] = scale;
    ss[128 + c] = beta[c] - mean * scale;
}

// out = relu(y*scale + shift), 8 elems/thread, bf16->bf16
__global__ __launch_bounds__(256) void bnrelu_kernel(
    const unsigned short* __restrict__ y, const float* __restrict__ ss,
    unsigned short* __restrict__ out)
{
    const size_t base = ((size_t)blockIdx.x * 256 + threadIdx.x) * 8;
    if (base >= (size_t)NN * HD) return;
    const int c = (int)(base & 127);
    mu32x4 v = *(const mu32x4*)(y + base);
    mf32x4 sc0 = *(const mf32x4*)(ss + c);
    mf32x4 sc1 = *(const mf32x4*)(ss + c + 4);
    mf32x4 sh0 = *(const mf32x4*)(ss + 128 + c);
    mf32x4 sh1 = *(const mf32x4*)(ss + 128 + c + 4);
    mu16x4 oa, ob;
    oa[0] = f2bf(fmaxf(bf2f_lo(v[0]) * sc0[0] + sh0[0], 0.f));
    oa[1] = f2bf(fmaxf(bf2f_hi(v[0]) * sc0[1] + sh0[1], 0.f));
    oa[2] = f2bf(fmaxf(bf2f_lo(v[1]) * sc0[2] + sh0[2], 0.f));
    oa[3] = f2bf(fmaxf(bf2f_hi(v[1]) * sc0[3] + sh0[3], 0.f));
    ob[0] = f2bf(fmaxf(bf2f_lo(v[2]) * sc1[0] + sh1[0], 0.f));
    ob[1] = f2bf(fmaxf(bf2f_hi(v[2]) * sc1[1] + sh1[1], 0.f));
    ob[2] = f2bf(fmaxf(bf2f_lo(v[3]) * sc1[2] + sh1[2], 0.f));
    ob[3] = f2bf(fmaxf(bf2f_hi(v[3]) * sc1[3] + sh1[3], 0.f));
    *(mu16x4*)(out + base) = oa;
    *(mu16x4*)(out + base + 4) = ob;
}

// graph start offsets from sorted batch_index
__global__ void starts_kernel(const int* __restrict__ batch, int* __restrict__ start)
{
    const int n = blockIdx.x * blockDim.x + threadIdx.x;
    if (n >= NN) return;
    int b = batch[n];
    int pb = (n == 0) ? -1 : batch[n - 1];
    if (b > NG - 1) b = NG - 1;
    if (pb > NG - 1) pb = NG - 1;
    for (int g = pb + 1; g <= b; g++) start[g] = n;
    if (n == NN - 1)
        for (int g = b + 1; g <= NG; g++) start[g] = NN;
}

// pooled[g] = sum of h rows (bf16) in [start[g], start[g+1])
__global__ __launch_bounds__(128) void pool_kernel(
    const unsigned short* __restrict__ h, const int* __restrict__ start,
    float* __restrict__ pooled)
{
    const int g = blockIdx.x, c = threadIdx.x;
    int s = start[g], e = start[g + 1];
    if (s < 0) s = 0;
    if (e > NN) e = NN;
    float acc = 0.f;
    for (int n = s; n < e; n++) acc += bf2f(h[(size_t)n * 128 + c]);
    pooled[(size_t)g * 128 + c] = acc;
}

// out[g][o] = pooled[g] . proj_W[:,o] + proj_b[o]   (fp32)
__global__ __launch_bounds__(256) void final_kernel(
    const float* __restrict__ pooled, const float* __restrict__ pw,
    const float* __restrict__ pb, float* __restrict__ out)
{
    __shared__ float pl[128];
    const int g = blockIdx.x, o = threadIdx.x;
    if (o < 128) pl[o] = pooled[(size_t)g * 128 + o];
    __syncthreads();
    float acc = pb[o];
#pragma unroll 4
    for (int k = 0; k < 128; k++) acc += pl[k] * pw[k * 256 + o];
    out[(size_t)g * 256 + o] = acc;
}

// ---------------------------------------------------------------------------
extern "C" void kernel_launch(void* const* d_in, const int* in_sizes, int n_in,
                              void* d_out, int out_size, void* d_ws, size_t ws_size,
                              hipStream_t stream)
{
    const float* x      = (const float*)d_in[0];
    const int*   edge   = (const int*)d_in[1];
    const int*   batch  = (const int*)d_in[2];
    const float* emb_W  = (const float*)d_in[4];
    const float* emb_b  = (const float*)d_in[5];
    const float* W1     = (const float*)d_in[6];
    const float* b1     = (const float*)d_in[7];
    const float* g1     = (const float*)d_in[8];
    const float* be1    = (const float*)d_in[9];
    const float* W2     = (const float*)d_in[10];
    const float* b2     = (const float*)d_in[11];
    const float* g2     = (const float*)d_in[12];
    const float* be2    = (const float*)d_in[13];
    const float* eps    = (const float*)d_in[14];
    const float* proj_W = (const float*)d_in[15];
    const float* proj_b = (const float*)d_in[16];
    float* out = (float*)d_out;

    char* ws = (char*)d_ws;
    size_t off = 0;
    auto take = [&](size_t bytes) -> char* {
        char* p = ws + off;
        off += (bytes + 255) & ~(size_t)255;
        return p;
    };
    float*          stats  = (float*)take(6 * 2 * HD * 4);       // 6 KB
    float*          ss     = (float*)take(6 * 2 * HD * 4);       // 6 KB
    int*            start  = (int*)take((NG + 1) * 4);           // 4 KB
    float*          pooled = (float*)take((size_t)NG * HD * 4);  // 512 KB
    int*            rowptr = (int*)take((NN + 1) * 4);           // 200 KB
    int*            cursor = (int*)take(NN * 4);                 // 200 KB
    int*            adj    = (int*)take((size_t)NE * 4);         // 2.4 MB
    unsigned short* h      = (unsigned short*)take((size_t)NN * HD * 2);  // 12.8 MB
    unsigned short* ybuf   = (unsigned short*)take((size_t)NN * HD * 2);  // 12.8 MB
    unsigned short* z2     = (unsigned short*)take((size_t)NN * HD * 2);  // 12.8 MB

    hipMemsetAsync(stats, 0, 6 * 2 * HD * 4, stream);
    hipMemsetAsync(cursor, 0, NN * 4, stream);

    const int gemm_grid = (NN + 63) / 64;       // 782
    const int ew_grid   = (NN * HD / 8) / 256;  // 3125
    const float inv_n = 1.0f / (float)NN;

    // ---- CSR build (once; edges constant across layers) ----
    deg_kernel<<<(NE + 255) / 256, 256, 0, stream>>>(edge, cursor);
    scan_kernel<<<1, 1024, 0, stream>>>(cursor, rowptr);
    fill_kernel<<<(NE + 255) / 256, 256, 0, stream>>>(edge, cursor, adj);

    // embed: h = x @ emb_W + emb_b   (x fp32, K=64)
    gemm_kernel<AD, false><<<gemm_grid, 256, 0, stream>>>(x, emb_W, emb_b, h, NN);

    for (int l = 0; l < 3; l++) {
        gather_kernel<<<(NN + 1) / 2, 256, 0, stream>>>(h, rowptr, adj, eps, l, z2);
        gemm_kernel<HD, true><<<gemm_grid, 256, 0, stream>>>(
            z2, W1 + (size_t)l * HD * HD, b1 + l * HD, ybuf, NN);
        stats_kernel<<<256, 256, 0, stream>>>(ybuf, stats + (2 * l) * 256, NN);
        finalize_kernel<<<1, 128, 0, stream>>>(stats + (2 * l) * 256, g1 + l * HD,
                                               be1 + l * HD, ss + (2 * l) * 256, inv_n);
        bnrelu_kernel<<<ew_grid, 256, 0, stream>>>(ybuf, ss + (2 * l) * 256, z2);
        gemm_kernel<HD, true><<<gemm_grid, 256, 0, stream>>>(
            z2, W2 + (size_t)l * HD * HD, b2 + l * HD, ybuf, NN);
        stats_kernel<<<256, 256, 0, stream>>>(ybuf, stats + (2 * l + 1) * 256, NN);
        finalize_kernel<<<1, 128, 0, stream>>>(stats + (2 * l + 1) * 256, g2 + l * HD,
                                               be2 + l * HD, ss + (2 * l + 1) * 256, inv_n);
        bnrelu_kernel<<<ew_grid, 256, 0, stream>>>(ybuf, ss + (2 * l + 1) * 256, h);
    }

    starts_kernel<<<(NN + 255) / 256, 256, 0, stream>>>(batch, start);
    pool_kernel<<<NG, 128, 0, stream>>>(h, start, pooled);
    final_kernel<<<NG, 256, 0, stream>>>(pooled, proj_W, proj_b, out);
}

// Round 5
// 632.094 us; speedup vs baseline: 10.7266x; 1.3717x over previous
//
#include <hip/hip_runtime.h>
#include <stdint.h>

#define NN 50000   // nodes
#define NE 600000  // edges
#define NG 1000    // graphs
#define AD 64      // input feat
#define HD 128     // hidden
#define OD 256     // output
#define BN_EPS_F 1e-5f
#define INV_N (1.0f / 50000.0f)
#define NB 196     // scan blocks = ceil(NN/256)

typedef __attribute__((ext_vector_type(8))) short  mbf16x8;
typedef __attribute__((ext_vector_type(4))) float  mf32x4;
typedef __attribute__((ext_vector_type(4))) unsigned short mu16x4;
typedef __attribute__((ext_vector_type(4))) unsigned int   mu32x4;

__device__ __forceinline__ float bf2f(unsigned short u) {
    union { unsigned int i; float f; } v; v.i = ((unsigned int)u) << 16; return v.f;
}
__device__ __forceinline__ unsigned short f2bf(float f) {
    union { float f; unsigned int i; } v; v.f = f;
    unsigned int r = v.i + 0x7fffu + ((v.i >> 16) & 1u);  // RNE
    return (unsigned short)(r >> 16);
}
// BN (scale, shift) for column c from raw sums
__device__ __forceinline__ void bn_ss(
    const float* __restrict__ stats, const float* __restrict__ gamma,
    const float* __restrict__ beta, int c, float& sc, float& sh)
{
    const float mean = stats[c] * INV_N;
    const float var = fmaxf(stats[128 + c] * INV_N - mean * mean, 0.f);
    const float inv = rsqrtf(var + BN_EPS_F);
    sc = gamma[c] * inv;
    sh = beta[c] - mean * sc;
}

// ---------------------------------------------------------------------------
// Weight pre-convert + transpose: wt[n][k] bf16 from W[k][n] fp32.
// layout: [emb 128x64][W1_0..2 128x128][W2_0..2 128x128]
// ---------------------------------------------------------------------------
__global__ __launch_bounds__(256) void prew_kernel(
    const float* __restrict__ emb_W, const float* __restrict__ W1,
    const float* __restrict__ W2, unsigned short* __restrict__ wt)
{
    const int t = blockIdx.x * 256 + threadIdx.x;
    if (t < 8192) {                    // emb: n=t>>6, k=t&63
        wt[t] = f2bf(emb_W[(t & 63) * 128 + (t >> 6)]);
    } else {
        const int t2 = t - 8192;
        if (t2 >= 6 * 16384) return;
        const int which = t2 >> 14, o = t2 & 16383;
        const int n = o >> 7, k = o & 127;
        const float* src = (which < 3) ? (W1 + (size_t)which * 16384)
                                       : (W2 + (size_t)(which - 3) * 16384);
        wt[t] = f2bf(src[k * 128 + n]);
    }
}

// ---------------------------------------------------------------------------
// GEMM: out_bf16[N,128] = A[N,K] @ Wt^T + bias
// AMODE: 0 = A fp32, 1 = A bf16, 2 = A bf16 with BN(stats_in)+ReLU on the fly
// SOUT:  epilogue accumulates per-column sum/sumsq (fp32 acc) into stats_out
// ---------------------------------------------------------------------------
template <int K, int AMODE, bool SOUT>
__global__ __launch_bounds__(256) void gemm_kernel(
    const void* __restrict__ in, const unsigned short* __restrict__ Wt,
    const float* __restrict__ bias, const float* __restrict__ stats_in,
    const float* __restrict__ gamma, const float* __restrict__ beta,
    unsigned short* __restrict__ out, float* __restrict__ stats_out, int n_rows)
{
    constexpr int SA = K + 8, SB = K + 8;
    __shared__ unsigned short zs[64 * SA];
    __shared__ unsigned short ws[128 * SB];
    __shared__ float ssl[128], ssh[128];
    __shared__ float lsum[128], lsq[128];

    const int tid = threadIdx.x;
    const int wave = tid >> 6, lane = tid & 63;
    const int row0 = blockIdx.x * 64;

    if (SOUT && tid < 128) { lsum[tid] = 0.f; lsq[tid] = 0.f; }
    if (AMODE == 2) {
        if (tid < 128) {
            float sc, sh; bn_ss(stats_in, gamma, beta, tid, sc, sh);
            ssl[tid] = sc; ssh[tid] = sh;
        }
        __syncthreads();
    }

    // ---- stage Wt (bf16 [n][k]) -> LDS, 16B vectors ----
    constexpr int NSH = (K == 128) ? 7 : 6;
    for (int i = tid; i < 128 * K / 8; i += 256) {
        const int base = i * 8;
        const int n = base >> NSH, k = base & (K - 1);
        *(mu32x4*)(&ws[n * SB + k]) = *(const mu32x4*)(Wt + base);
    }

    // ---- stage A tile -> LDS ----
    if constexpr (AMODE == 0) {
        const float* src = (const float*)in;
        constexpr int LPR = K / 4;
        for (int i = tid; i < 64 * LPR; i += 256) {
            const int r = i / LPR, c4 = (i % LPR) * 4;
            mf32x4 v = {0.f, 0.f, 0.f, 0.f};
            if (row0 + r < n_rows)
                v = *(const mf32x4*)(src + (size_t)(row0 + r) * K + c4);
            mu16x4 o;
            o[0] = f2bf(v[0]); o[1] = f2bf(v[1]); o[2] = f2bf(v[2]); o[3] = f2bf(v[3]);
            *(mu16x4*)(&zs[r * SA + c4]) = o;
        }
    } else {
        const unsigned short* src = (const unsigned short*)in;
        constexpr int LPR = K / 8;
        float sc[8], sh[8];
        if constexpr (AMODE == 2) {
            const int c8 = (tid % LPR) * 8;   // fixed per thread (stride 256 = mult of LPR)
#pragma unroll
            for (int j = 0; j < 8; j++) { sc[j] = ssl[c8 + j]; sh[j] = ssh[c8 + j]; }
        }
        for (int i = tid; i < 64 * LPR; i += 256) {
            const int r = i / LPR, c8 = (i % LPR) * 8;
            mu32x4 v = {0, 0, 0, 0};
            if (row0 + r < n_rows)
                v = *(const mu32x4*)(src + (size_t)(row0 + r) * K + c8);
            if constexpr (AMODE == 2) {
                const unsigned short* u = (const unsigned short*)&v;
                mu16x4 oa, ob;
#pragma unroll
                for (int j = 0; j < 4; j++)
                    oa[j] = f2bf(fmaxf(bf2f(u[j]) * sc[j] + sh[j], 0.f));
#pragma unroll
                for (int j = 0; j < 4; j++)
                    ob[j] = f2bf(fmaxf(bf2f(u[4 + j]) * sc[4 + j] + sh[4 + j], 0.f));
                *(mu16x4*)(&zs[r * SA + c8]) = oa;
                *(mu16x4*)(&zs[r * SA + c8 + 4]) = ob;
            } else {
                *(mu32x4*)(&zs[r * SA + c8]) = v;
            }
        }
    }
    __syncthreads();

    // ---- MFMA ----
    mf32x4 acc[8];
#pragma unroll
    for (int t = 0; t < 8; t++) acc[t] = {0.f, 0.f, 0.f, 0.f};
    const int m = wave * 16 + (lane & 15);
    const int kq = (lane >> 4) * 8;
#pragma unroll
    for (int kk = 0; kk < K / 32; kk++) {
        const int k0 = kk * 32 + kq;
        mbf16x8 a = *(const mbf16x8*)(&zs[m * SA + k0]);
#pragma unroll
        for (int t = 0; t < 8; t++) {
            const int n = t * 16 + (lane & 15);
            mbf16x8 b = *(const mbf16x8*)(&ws[n * SB + k0]);
            acc[t] = __builtin_amdgcn_mfma_f32_16x16x32_bf16(a, b, acc[t], 0, 0, 0);
        }
    }

    // ---- epilogue: +bias, store bf16; fused column stats from fp32 acc ----
    const int rbase = wave * 16 + ((lane >> 4) << 2);
#pragma unroll
    for (int t = 0; t < 8; t++) {
        const int c = t * 16 + (lane & 15);
        const float bv = bias[c];
        float s = 0.f, q = 0.f;
#pragma unroll
        for (int r = 0; r < 4; r++) {
            const int grow = row0 + rbase + r;
            const float y = acc[t][r] + bv;
            if (grow < n_rows) {
                out[(size_t)grow * 128 + c] = f2bf(y);
                if (SOUT) { s += y; q += y * y; }
            }
        }
        if (SOUT) {
            s += __shfl_xor(s, 16); s += __shfl_xor(s, 32);
            q += __shfl_xor(q, 16); q += __shfl_xor(q, 32);
            if ((lane >> 4) == 0) {
                atomicAdd(&lsum[c], s);
                atomicAdd(&lsq[c], q);
            }
        }
    }
    if (SOUT) {
        __syncthreads();
        if (tid < 128) {
            atomicAdd(&stats_out[tid], lsum[tid]);
            atomicAdd(&stats_out[128 + tid], lsq[tid]);
        }
    }
}

// ---------------------------------------------------------------------------
// CSR build: histogram -> 3-phase parallel scan -> fill
// ---------------------------------------------------------------------------
__global__ __launch_bounds__(256) void deg_kernel(
    const int* __restrict__ ei, int* __restrict__ deg)
{
    const int e = blockIdx.x * 256 + threadIdx.x;
    if (e >= NE) return;
    const int row = ei[e];
    if ((unsigned)row < NN) atomicAdd(&deg[row], 1);
}

__global__ __launch_bounds__(256) void bscan_kernel(
    const int* __restrict__ deg, int* __restrict__ rowptr, int* __restrict__ bsum)
{
    __shared__ int sm[256];
    const int t = threadIdx.x, idx = blockIdx.x * 256 + t;
    const int d = (idx < NN) ? deg[idx] : 0;
    sm[t] = d; __syncthreads();
    for (int ofs = 1; ofs < 256; ofs <<= 1) {
        int v = (t >= ofs) ? sm[t - ofs] : 0;
        __syncthreads();
        sm[t] += v;
        __syncthreads();
    }
    if (idx < NN) rowptr[idx] = sm[t] - d;  // exclusive
    if (t == 255) bsum[blockIdx.x] = sm[255];
}

__global__ __launch_bounds__(256) void off_kernel(
    const int* __restrict__ bsum, int* __restrict__ boff, int* __restrict__ rowptr)
{
    __shared__ int sm[256];
    const int t = threadIdx.x;
    const int d = (t < NB) ? bsum[t] : 0;
    sm[t] = d; __syncthreads();
    for (int ofs = 1; ofs < 256; ofs <<= 1) {
        int v = (t >= ofs) ? sm[t - ofs] : 0;
        __syncthreads();
        sm[t] += v;
        __syncthreads();
    }
    if (t < NB) boff[t] = sm[t] - d;
    if (t == 255) rowptr[NN] = sm[255];
}

__global__ __launch_bounds__(256) void addoff_kernel(
    int* __restrict__ rowptr, const int* __restrict__ boff, int* __restrict__ cursor)
{
    const int idx = blockIdx.x * 256 + threadIdx.x;
    if (idx >= NN) return;
    const int v = rowptr[idx] + boff[idx >> 8];
    rowptr[idx] = v;
    cursor[idx] = v;
}

__global__ __launch_bounds__(256) void fill_kernel(
    const int* __restrict__ ei, int* __restrict__ cursor, int* __restrict__ adj)
{
    const int e = blockIdx.x * 256 + threadIdx.x;
    if (e >= NE) return;
    const int row = ei[e];
    const int col = ei[NE + e];
    if ((unsigned)row >= NN || (unsigned)col >= NN) return;
    adj[atomicAdd(&cursor[row], 1)] = col;
}

// ---------------------------------------------------------------------------
// gather: z[n] = (1+eps[l])*f(src[n]) + sum_{c in adj[n]} f(src[c])
// f = BN+ReLU (per-column, from raw stats) when BN, else identity.
// 2 nodes / 256-thread block, 128 threads per node.
// ---------------------------------------------------------------------------
template <bool BN>
__global__ __launch_bounds__(256) void gather_kernel(
    const unsigned short* __restrict__ src, const int* __restrict__ rowptr,
    const int* __restrict__ adj, const float* __restrict__ stats,
    const float* __restrict__ gamma, const float* __restrict__ beta,
    const float* __restrict__ eps, int l, unsigned short* __restrict__ z)
{
    const int node = blockIdx.x * 2 + (threadIdx.x >> 7);
    const int c = threadIdx.x & 127;
    if (node >= NN) return;
    float sc = 1.f, sh = 0.f;
    if (BN) bn_ss(stats, gamma, beta, c, sc, sh);
    const float e = 1.0f + eps[l];
    auto ld = [&](int n) -> float {
        const float v = bf2f(src[(size_t)n * HD + c]);
        return BN ? fmaxf(v * sc + sh, 0.f) : v;
    };
    float acc = e * ld(node);
    const int s = rowptr[node], t = rowptr[node + 1];
    int i = s;
    for (; i + 1 < t; i += 2) {
        const int c0 = adj[i], c1 = adj[i + 1];
        acc += ld(c0);
        acc += ld(c1);
    }
    if (i < t) acc += ld(adj[i]);
    z[(size_t)node * HD + c] = f2bf(acc);
}

// graph start offsets from sorted batch_index
__global__ void starts_kernel(const int* __restrict__ batch, int* __restrict__ start)
{
    const int n = blockIdx.x * blockDim.x + threadIdx.x;
    if (n >= NN) return;
    int b = batch[n];
    int pb = (n == 0) ? -1 : batch[n - 1];
    if (b > NG - 1) b = NG - 1;
    if (pb > NG - 1) pb = NG - 1;
    for (int g = pb + 1; g <= b; g++) start[g] = n;
    if (n == NN - 1)
        for (int g = b + 1; g <= NG; g++) start[g] = NN;
}

// pooled[g] = sum over graph rows of BN+ReLU(y)   (final BN fused here)
__global__ __launch_bounds__(128) void pool_kernel(
    const unsigned short* __restrict__ y, const int* __restrict__ start,
    const float* __restrict__ stats, const float* __restrict__ gamma,
    const float* __restrict__ beta, float* __restrict__ pooled)
{
    const int g = blockIdx.x, c = threadIdx.x;
    float sc, sh; bn_ss(stats, gamma, beta, c, sc, sh);
    int s = start[g], e = start[g + 1];
    if (s < 0) s = 0;
    if (e > NN) e = NN;
    float acc = 0.f;
    for (int n = s; n < e; n++)
        acc += fmaxf(bf2f(y[(size_t)n * 128 + c]) * sc + sh, 0.f);
    pooled[(size_t)g * 128 + c] = acc;
}

// out[g][o] = pooled[g] . proj_W[:,o] + proj_b[o]   (fp32)
__global__ __launch_bounds__(256) void final_kernel(
    const float* __restrict__ pooled, const float* __restrict__ pw,
    const float* __restrict__ pb, float* __restrict__ out)
{
    __shared__ float pl[128];
    const int g = blockIdx.x, o = threadIdx.x;
    if (o < 128) pl[o] = pooled[(size_t)g * 128 + o];
    __syncthreads();
    float acc = pb[o];
#pragma unroll 4
    for (int k = 0; k < 128; k++) acc += pl[k] * pw[k * 256 + o];
    out[(size_t)g * 256 + o] = acc;
}

// ---------------------------------------------------------------------------
extern "C" void kernel_launch(void* const* d_in, const int* in_sizes, int n_in,
                              void* d_out, int out_size, void* d_ws, size_t ws_size,
                              hipStream_t stream)
{
    const float* x      = (const float*)d_in[0];
    const int*   edge   = (const int*)d_in[1];
    const int*   batch  = (const int*)d_in[2];
    const float* emb_W  = (const float*)d_in[4];
    const float* emb_b  = (const float*)d_in[5];
    const float* W1     = (const float*)d_in[6];
    const float* b1     = (const float*)d_in[7];
    const float* g1     = (const float*)d_in[8];
    const float* be1    = (const float*)d_in[9];
    const float* W2     = (const float*)d_in[10];
    const float* b2     = (const float*)d_in[11];
    const float* g2     = (const float*)d_in[12];
    const float* be2    = (const float*)d_in[13];
    const float* eps    = (const float*)d_in[14];
    const float* proj_W = (const float*)d_in[15];
    const float* proj_b = (const float*)d_in[16];
    float* out = (float*)d_out;

    char* ws = (char*)d_ws;
    size_t off = 0;
    auto take = [&](size_t bytes) -> char* {
        char* p = ws + off;
        off += (bytes + 255) & ~(size_t)255;
        return p;
    };
    float*          stats  = (float*)take(6 * 2 * HD * 4);
    int*            start  = (int*)take((NG + 1) * 4);
    int*            deg    = (int*)take(NN * 4);
    int*            rowptr = (int*)take((NN + 1) * 4);
    int*            cursor = (int*)take(NN * 4);
    int*            bsum   = (int*)take(256 * 4);
    int*            boff   = (int*)take(256 * 4);
    float*          pooled = (float*)take((size_t)NG * HD * 4);
    unsigned short* wt     = (unsigned short*)take((size_t)(8192 + 6 * 16384) * 2);
    int*            adj    = (int*)take((size_t)NE * 4);
    unsigned short* zbuf   = (unsigned short*)take((size_t)NN * HD * 2);
    unsigned short* y1buf  = (unsigned short*)take((size_t)NN * HD * 2);
    unsigned short* y2buf  = (unsigned short*)take((size_t)NN * HD * 2);

    hipMemsetAsync(stats, 0, 6 * 2 * HD * 4, stream);
    hipMemsetAsync(deg, 0, NN * 4, stream);

    const int gemm_grid = (NN + 63) / 64;  // 782

    // weight pre-convert/transpose + CSR build
    prew_kernel<<<(8192 + 6 * 16384 + 255) / 256, 256, 0, stream>>>(emb_W, W1, W2, wt);
    deg_kernel<<<(NE + 255) / 256, 256, 0, stream>>>(edge, deg);
    bscan_kernel<<<NB, 256, 0, stream>>>(deg, rowptr, bsum);
    off_kernel<<<1, 256, 0, stream>>>(bsum, boff, rowptr);
    addoff_kernel<<<NB, 256, 0, stream>>>(rowptr, boff, cursor);
    fill_kernel<<<(NE + 255) / 256, 256, 0, stream>>>(edge, cursor, adj);

    // embed: y2buf = x @ emb_W + emb_b  (gather-src role)
    gemm_kernel<AD, 0, false><<<gemm_grid, 256, 0, stream>>>(
        x, wt, emb_b, nullptr, nullptr, nullptr, y2buf, nullptr, NN);

    for (int l = 0; l < 3; l++) {
        if (l == 0)
            gather_kernel<false><<<(NN + 1) / 2, 256, 0, stream>>>(
                y2buf, rowptr, adj, stats, g2, be2, eps, l, zbuf);
        else
            gather_kernel<true><<<(NN + 1) / 2, 256, 0, stream>>>(
                y2buf, rowptr, adj, stats + (2 * l - 1) * 256,
                g2 + (l - 1) * HD, be2 + (l - 1) * HD, eps, l, zbuf);
        gemm_kernel<HD, 1, true><<<gemm_grid, 256, 0, stream>>>(
            zbuf, wt + 8192 + (size_t)l * 16384, b1 + l * HD,
            nullptr, nullptr, nullptr, y1buf, stats + (2 * l) * 256, NN);
        gemm_kernel<HD, 2, true><<<gemm_grid, 256, 0, stream>>>(
            y1buf, wt + 8192 + (size_t)(3 + l) * 16384, b2 + l * HD,
            stats + (2 * l) * 256, g1 + l * HD, be1 + l * HD,
            y2buf, stats + (2 * l + 1) * 256, NN);
    }

    starts_kernel<<<(NN + 255) / 256, 256, 0, stream>>>(batch, start);
    pool_kernel<<<NG, 128, 0, stream>>>(y2buf, start, stats + 5 * 256,
                                        g2 + 2 * HD, be2 + 2 * HD, pooled);
    final_kernel<<<NG, 256, 0, stream>>>(pooled, proj_W, proj_b, out);
}

// Round 6
// 490.999 us; speedup vs baseline: 13.8091x; 1.2874x over previous
//
#include <hip/hip_runtime.h>
#include <stdint.h>

#define NN 50000   // nodes
#define NE 600000  // edges
#define NG 1000    // graphs
#define AD 64      // input feat
#define HD 128     // hidden
#define OD 256     // output
#define BN_EPS_F 1e-5f
#define INV_N (1.0f / 50000.0f)
#define NB 196     // scan blocks = ceil(NN/256)

typedef __attribute__((ext_vector_type(8))) short  mbf16x8;
typedef __attribute__((ext_vector_type(4))) float  mf32x4;
typedef __attribute__((ext_vector_type(4))) unsigned short mu16x4;
typedef __attribute__((ext_vector_type(4))) unsigned int   mu32x4;

__device__ __forceinline__ float bf2f(unsigned short u) {
    union { unsigned int i; float f; } v; v.i = ((unsigned int)u) << 16; return v.f;
}
__device__ __forceinline__ unsigned short f2bf(float f) {
    union { float f; unsigned int i; } v; v.f = f;
    unsigned int r = v.i + 0x7fffu + ((v.i >> 16) & 1u);  // RNE
    return (unsigned short)(r >> 16);
}
// BN (scale, shift) for column c from raw sums
__device__ __forceinline__ void bn_ss(
    const float* __restrict__ stats, const float* __restrict__ gamma,
    const float* __restrict__ beta, int c, float& sc, float& sh)
{
    const float mean = stats[c] * INV_N;
    const float var = fmaxf(stats[128 + c] * INV_N - mean * mean, 0.f);
    const float inv = rsqrtf(var + BN_EPS_F);
    sc = gamma[c] * inv;
    sh = beta[c] - mean * sc;
}

// ---------------------------------------------------------------------------
// Weight pre-convert + transpose: wt[n][k] bf16 from W[k][n] fp32.
// layout: [emb 128x64][W1_0..2 128x128][W2_0..2 128x128]
// ---------------------------------------------------------------------------
__global__ __launch_bounds__(256) void prew_kernel(
    const float* __restrict__ emb_W, const float* __restrict__ W1,
    const float* __restrict__ W2, unsigned short* __restrict__ wt)
{
    const int t = blockIdx.x * 256 + threadIdx.x;
    if (t < 8192) {                    // emb: n=t>>6, k=t&63
        wt[t] = f2bf(emb_W[(t & 63) * 128 + (t >> 6)]);
    } else {
        const int t2 = t - 8192;
        if (t2 >= 6 * 16384) return;
        const int which = t2 >> 14, o = t2 & 16383;
        const int n = o >> 7, k = o & 127;
        const float* src = (which < 3) ? (W1 + (size_t)which * 16384)
                                       : (W2 + (size_t)(which - 3) * 16384);
        wt[t] = f2bf(src[k * 128 + n]);
    }
}

// ---------------------------------------------------------------------------
// GEMM: out_bf16[N,128] = A[N,K] @ Wt^T + bias
// AMODE: 0 = A fp32, 1 = A bf16, 2 = A bf16 with BN(stats_in)+ReLU on the fly
// SOUT:  epilogue accumulates per-column sum/sumsq (fp32 acc) into stats_out
// ---------------------------------------------------------------------------
template <int K, int AMODE, bool SOUT>
__global__ __launch_bounds__(256) void gemm_kernel(
    const void* __restrict__ in, const unsigned short* __restrict__ Wt,
    const float* __restrict__ bias, const float* __restrict__ stats_in,
    const float* __restrict__ gamma, const float* __restrict__ beta,
    unsigned short* __restrict__ out, float* __restrict__ stats_out, int n_rows)
{
    constexpr int SA = K + 8, SB = K + 8;
    __shared__ unsigned short zs[64 * SA];
    __shared__ unsigned short ws[128 * SB];
    __shared__ float ssl[128], ssh[128];
    __shared__ float lsum[128], lsq[128];

    const int tid = threadIdx.x;
    const int wave = tid >> 6, lane = tid & 63;
    const int row0 = blockIdx.x * 64;

    if (SOUT && tid < 128) { lsum[tid] = 0.f; lsq[tid] = 0.f; }
    if (AMODE == 2) {
        if (tid < 128) {
            float sc, sh; bn_ss(stats_in, gamma, beta, tid, sc, sh);
            ssl[tid] = sc; ssh[tid] = sh;
        }
        __syncthreads();
    }

    // ---- stage Wt (bf16 [n][k]) -> LDS, 16B vectors ----
    constexpr int NSH = (K == 128) ? 7 : 6;
    for (int i = tid; i < 128 * K / 8; i += 256) {
        const int base = i * 8;
        const int n = base >> NSH, k = base & (K - 1);
        *(mu32x4*)(&ws[n * SB + k]) = *(const mu32x4*)(Wt + base);
    }

    // ---- stage A tile -> LDS ----
    if constexpr (AMODE == 0) {
        const float* src = (const float*)in;
        constexpr int LPR = K / 4;
        for (int i = tid; i < 64 * LPR; i += 256) {
            const int r = i / LPR, c4 = (i % LPR) * 4;
            mf32x4 v = {0.f, 0.f, 0.f, 0.f};
            if (row0 + r < n_rows)
                v = *(const mf32x4*)(src + (size_t)(row0 + r) * K + c4);
            mu16x4 o;
            o[0] = f2bf(v[0]); o[1] = f2bf(v[1]); o[2] = f2bf(v[2]); o[3] = f2bf(v[3]);
            *(mu16x4*)(&zs[r * SA + c4]) = o;
        }
    } else {
        const unsigned short* src = (const unsigned short*)in;
        constexpr int LPR = K / 8;
        float sc[8], sh[8];
        if constexpr (AMODE == 2) {
            const int c8 = (tid % LPR) * 8;
#pragma unroll
            for (int j = 0; j < 8; j++) { sc[j] = ssl[c8 + j]; sh[j] = ssh[c8 + j]; }
        }
        for (int i = tid; i < 64 * LPR; i += 256) {
            const int r = i / LPR, c8 = (i % LPR) * 8;
            mu32x4 v = {0, 0, 0, 0};
            if (row0 + r < n_rows)
                v = *(const mu32x4*)(src + (size_t)(row0 + r) * K + c8);
            if constexpr (AMODE == 2) {
                const unsigned short* u = (const unsigned short*)&v;
                mu16x4 oa, ob;
#pragma unroll
                for (int j = 0; j < 4; j++)
                    oa[j] = f2bf(fmaxf(bf2f(u[j]) * sc[j] + sh[j], 0.f));
#pragma unroll
                for (int j = 0; j < 4; j++)
                    ob[j] = f2bf(fmaxf(bf2f(u[4 + j]) * sc[4 + j] + sh[4 + j], 0.f));
                *(mu16x4*)(&zs[r * SA + c8]) = oa;
                *(mu16x4*)(&zs[r * SA + c8 + 4]) = ob;
            } else {
                *(mu32x4*)(&zs[r * SA + c8]) = v;
            }
        }
    }
    __syncthreads();

    // ---- MFMA ----
    mf32x4 acc[8];
#pragma unroll
    for (int t = 0; t < 8; t++) acc[t] = {0.f, 0.f, 0.f, 0.f};
    const int m = wave * 16 + (lane & 15);
    const int kq = (lane >> 4) * 8;
#pragma unroll
    for (int kk = 0; kk < K / 32; kk++) {
        const int k0 = kk * 32 + kq;
        mbf16x8 a = *(const mbf16x8*)(&zs[m * SA + k0]);
#pragma unroll
        for (int t = 0; t < 8; t++) {
            const int n = t * 16 + (lane & 15);
            mbf16x8 b = *(const mbf16x8*)(&ws[n * SB + k0]);
            acc[t] = __builtin_amdgcn_mfma_f32_16x16x32_bf16(a, b, acc[t], 0, 0, 0);
        }
    }

    // ---- epilogue: +bias, store bf16; fused column stats from fp32 acc ----
    const int rbase = wave * 16 + ((lane >> 4) << 2);
#pragma unroll
    for (int t = 0; t < 8; t++) {
        const int c = t * 16 + (lane & 15);
        const float bv = bias[c];
        float s = 0.f, q = 0.f;
#pragma unroll
        for (int r = 0; r < 4; r++) {
            const int grow = row0 + rbase + r;
            const float y = acc[t][r] + bv;
            if (grow < n_rows) {
                out[(size_t)grow * 128 + c] = f2bf(y);
                if (SOUT) { s += y; q += y * y; }
            }
        }
        if (SOUT) {
            s += __shfl_xor(s, 16); s += __shfl_xor(s, 32);
            q += __shfl_xor(q, 16); q += __shfl_xor(q, 32);
            if ((lane >> 4) == 0) {
                atomicAdd(&lsum[c], s);
                atomicAdd(&lsq[c], q);
            }
        }
    }
    if (SOUT) {
        __syncthreads();
        if (tid < 128) {
            atomicAdd(&stats_out[tid], lsum[tid]);
            atomicAdd(&stats_out[128 + tid], lsq[tid]);
        }
    }
}

// ---------------------------------------------------------------------------
// CSR build: histogram -> 3-phase parallel scan -> fill
// ---------------------------------------------------------------------------
__global__ __launch_bounds__(256) void deg_kernel(
    const int* __restrict__ ei, int* __restrict__ deg)
{
    const int e = blockIdx.x * 256 + threadIdx.x;
    if (e >= NE) return;
    const int row = ei[e];
    if ((unsigned)row < NN) atomicAdd(&deg[row], 1);
}

__global__ __launch_bounds__(256) void bscan_kernel(
    const int* __restrict__ deg, int* __restrict__ rowptr, int* __restrict__ bsum)
{
    __shared__ int sm[256];
    const int t = threadIdx.x, idx = blockIdx.x * 256 + t;
    const int d = (idx < NN) ? deg[idx] : 0;
    sm[t] = d; __syncthreads();
    for (int ofs = 1; ofs < 256; ofs <<= 1) {
        int v = (t >= ofs) ? sm[t - ofs] : 0;
        __syncthreads();
        sm[t] += v;
        __syncthreads();
    }
    if (idx < NN) rowptr[idx] = sm[t] - d;  // exclusive
    if (t == 255) bsum[blockIdx.x] = sm[255];
}

__global__ __launch_bounds__(256) void off_kernel(
    const int* __restrict__ bsum, int* __restrict__ boff, int* __restrict__ rowptr)
{
    __shared__ int sm[256];
    const int t = threadIdx.x;
    const int d = (t < NB) ? bsum[t] : 0;
    sm[t] = d; __syncthreads();
    for (int ofs = 1; ofs < 256; ofs <<= 1) {
        int v = (t >= ofs) ? sm[t - ofs] : 0;
        __syncthreads();
        sm[t] += v;
        __syncthreads();
    }
    if (t < NB) boff[t] = sm[t] - d;
    if (t == 255) rowptr[NN] = sm[255];
}

__global__ __launch_bounds__(256) void addoff_kernel(
    int* __restrict__ rowptr, const int* __restrict__ boff, int* __restrict__ cursor)
{
    const int idx = blockIdx.x * 256 + threadIdx.x;
    if (idx >= NN) return;
    const int v = rowptr[idx] + boff[idx >> 8];
    rowptr[idx] = v;
    cursor[idx] = v;
}

__global__ __launch_bounds__(256) void fill_kernel(
    const int* __restrict__ ei, int* __restrict__ cursor, int* __restrict__ adj)
{
    const int e = blockIdx.x * 256 + threadIdx.x;
    if (e >= NE) return;
    const int row = ei[e];
    const int col = ei[NE + e];
    if ((unsigned)row >= NN || (unsigned)col >= NN) return;
    adj[atomicAdd(&cursor[row], 1)] = col;
}

// ---------------------------------------------------------------------------
// gather: z[n] = (1+eps[l])*f(src[n]) + sum_{c in adj[n]} f(src[c])
// f = BN+ReLU (from raw stats) when BN, else identity.
// 16 threads/node x 16B loads; 16 nodes per 256-thread block.
// 4-neighbor unroll keeps 4 independent 16B loads in flight per thread.
// ---------------------------------------------------------------------------
template <bool BN>
__global__ __launch_bounds__(256) void gather_kernel(
    const unsigned short* __restrict__ src, const int* __restrict__ rowptr,
    const int* __restrict__ adj, const float* __restrict__ stats,
    const float* __restrict__ gamma, const float* __restrict__ beta,
    const float* __restrict__ eps, int l, unsigned short* __restrict__ z)
{
    const int node = blockIdx.x * 16 + (threadIdx.x >> 4);
    const int c0 = (threadIdx.x & 15) * 8;
    if (node >= NN) return;
    float sc[8], sh[8];
    if (BN) {
#pragma unroll
        for (int j = 0; j < 8; j++) bn_ss(stats, gamma, beta, c0 + j, sc[j], sh[j]);
    }
    const float e = 1.0f + eps[l];
    float acc[8];
    {
        mu32x4 v = *(const mu32x4*)(src + (size_t)node * HD + c0);
        const unsigned short* u = (const unsigned short*)&v;
#pragma unroll
        for (int j = 0; j < 8; j++) {
            float f = bf2f(u[j]);
            if (BN) f = fmaxf(f * sc[j] + sh[j], 0.f);
            acc[j] = e * f;
        }
    }
    const int s = rowptr[node], t = rowptr[node + 1];
    int i = s;
    for (; i + 4 <= t; i += 4) {
        const int n0 = adj[i], n1 = adj[i + 1], n2 = adj[i + 2], n3 = adj[i + 3];
        mu32x4 v0 = *(const mu32x4*)(src + (size_t)n0 * HD + c0);
        mu32x4 v1 = *(const mu32x4*)(src + (size_t)n1 * HD + c0);
        mu32x4 v2 = *(const mu32x4*)(src + (size_t)n2 * HD + c0);
        mu32x4 v3 = *(const mu32x4*)(src + (size_t)n3 * HD + c0);
        const unsigned short* u0 = (const unsigned short*)&v0;
        const unsigned short* u1 = (const unsigned short*)&v1;
        const unsigned short* u2 = (const unsigned short*)&v2;
        const unsigned short* u3 = (const unsigned short*)&v3;
#pragma unroll
        for (int j = 0; j < 8; j++) {
            float f0 = bf2f(u0[j]), f1 = bf2f(u1[j]);
            float f2 = bf2f(u2[j]), f3 = bf2f(u3[j]);
            if (BN) {
                f0 = fmaxf(f0 * sc[j] + sh[j], 0.f);
                f1 = fmaxf(f1 * sc[j] + sh[j], 0.f);
                f2 = fmaxf(f2 * sc[j] + sh[j], 0.f);
                f3 = fmaxf(f3 * sc[j] + sh[j], 0.f);
            }
            acc[j] += (f0 + f1) + (f2 + f3);
        }
    }
    for (; i < t; i++) {
        mu32x4 v = *(const mu32x4*)(src + (size_t)adj[i] * HD + c0);
        const unsigned short* u = (const unsigned short*)&v;
#pragma unroll
        for (int j = 0; j < 8; j++) {
            float f = bf2f(u[j]);
            if (BN) f = fmaxf(f * sc[j] + sh[j], 0.f);
            acc[j] += f;
        }
    }
    mu16x4 o0, o1;
#pragma unroll
    for (int j = 0; j < 4; j++) o0[j] = f2bf(acc[j]);
#pragma unroll
    for (int j = 0; j < 4; j++) o1[j] = f2bf(acc[4 + j]);
    *(mu16x4*)(z + (size_t)node * HD + c0) = o0;
    *(mu16x4*)(z + (size_t)node * HD + c0 + 4) = o1;
}

// graph start offsets from sorted batch_index
__global__ void starts_kernel(const int* __restrict__ batch, int* __restrict__ start)
{
    const int n = blockIdx.x * blockDim.x + threadIdx.x;
    if (n >= NN) return;
    int b = batch[n];
    int pb = (n == 0) ? -1 : batch[n - 1];
    if (b > NG - 1) b = NG - 1;
    if (pb > NG - 1) pb = NG - 1;
    for (int g = pb + 1; g <= b; g++) start[g] = n;
    if (n == NN - 1)
        for (int g = b + 1; g <= NG; g++) start[g] = NN;
}

// pooled[g] = sum over graph rows of BN+ReLU(y)   (final BN fused)
// 16 row-lanes x 16 feature-threads (8 feats each, 16B loads), LDS reduce.
__global__ __launch_bounds__(256) void pool_kernel(
    const unsigned short* __restrict__ y, const int* __restrict__ start,
    const float* __restrict__ stats, const float* __restrict__ gamma,
    const float* __restrict__ beta, float* __restrict__ pooled)
{
    const int g = blockIdx.x;
    const int rg = threadIdx.x >> 4;          // row group 0..15
    const int c0 = (threadIdx.x & 15) * 8;
    float sc[8], sh[8];
#pragma unroll
    for (int j = 0; j < 8; j++) bn_ss(stats, gamma, beta, c0 + j, sc[j], sh[j]);
    int s = start[g], e = start[g + 1];
    if (s < 0) s = 0;
    if (e > NN) e = NN;
    float acc[8];
#pragma unroll
    for (int j = 0; j < 8; j++) acc[j] = 0.f;
    for (int n = s + rg; n < e; n += 16) {
        mu32x4 v = *(const mu32x4*)(y + (size_t)n * HD + c0);
        const unsigned short* u = (const unsigned short*)&v;
#pragma unroll
        for (int j = 0; j < 8; j++)
            acc[j] += fmaxf(bf2f(u[j]) * sc[j] + sh[j], 0.f);
    }
    __shared__ float red[16][128];
#pragma unroll
    for (int j = 0; j < 8; j++) red[rg][c0 + j] = acc[j];
    __syncthreads();
    if (threadIdx.x < 128) {
        float a = 0.f;
#pragma unroll
        for (int k = 0; k < 16; k++) a += red[k][threadIdx.x];
        pooled[(size_t)g * 128 + threadIdx.x] = a;
    }
}

// out[g][o] = pooled[g] . proj_W[:,o] + proj_b[o]   (fp32)
__global__ __launch_bounds__(256) void final_kernel(
    const float* __restrict__ pooled, const float* __restrict__ pw,
    const float* __restrict__ pb, float* __restrict__ out)
{
    __shared__ float pl[128];
    const int g = blockIdx.x, o = threadIdx.x;
    if (o < 128) pl[o] = pooled[(size_t)g * 128 + o];
    __syncthreads();
    float acc = pb[o];
#pragma unroll 4
    for (int k = 0; k < 128; k++) acc += pl[k] * pw[k * 256 + o];
    out[(size_t)g * 256 + o] = acc;
}

// ---------------------------------------------------------------------------
extern "C" void kernel_launch(void* const* d_in, const int* in_sizes, int n_in,
                              void* d_out, int out_size, void* d_ws, size_t ws_size,
                              hipStream_t stream)
{
    const float* x      = (const float*)d_in[0];
    const int*   edge   = (const int*)d_in[1];
    const int*   batch  = (const int*)d_in[2];
    const float* emb_W  = (const float*)d_in[4];
    const float* emb_b  = (const float*)d_in[5];
    const float* W1     = (const float*)d_in[6];
    const float* b1     = (const float*)d_in[7];
    const float* g1     = (const float*)d_in[8];
    const float* be1    = (const float*)d_in[9];
    const float* W2     = (const float*)d_in[10];
    const float* b2     = (const float*)d_in[11];
    const float* g2     = (const float*)d_in[12];
    const float* be2    = (const float*)d_in[13];
    const float* eps    = (const float*)d_in[14];
    const float* proj_W = (const float*)d_in[15];
    const float* proj_b = (const float*)d_in[16];
    float* out = (float*)d_out;

    char* ws = (char*)d_ws;
    size_t off = 0;
    auto take = [&](size_t bytes) -> char* {
        char* p = ws + off;
        off += (bytes + 255) & ~(size_t)255;
        return p;
    };
    float*          stats  = (float*)take(6 * 2 * HD * 4);
    int*            start  = (int*)take((NG + 1) * 4);
    int*            deg    = (int*)take(NN * 4);
    int*            rowptr = (int*)take((NN + 1) * 4);
    int*            cursor = (int*)take(NN * 4);
    int*            bsum   = (int*)take(256 * 4);
    int*            boff   = (int*)take(256 * 4);
    float*          pooled = (float*)take((size_t)NG * HD * 4);
    unsigned short* wt     = (unsigned short*)take((size_t)(8192 + 6 * 16384) * 2);
    int*            adj    = (int*)take((size_t)NE * 4);
    unsigned short* zbuf   = (unsigned short*)take((size_t)NN * HD * 2);
    unsigned short* y1buf  = (unsigned short*)take((size_t)NN * HD * 2);
    unsigned short* y2buf  = (unsigned short*)take((size_t)NN * HD * 2);

    hipMemsetAsync(stats, 0, 6 * 2 * HD * 4, stream);
    hipMemsetAsync(deg, 0, NN * 4, stream);

    const int gemm_grid = (NN + 63) / 64;  // 782

    // weight pre-convert/transpose + CSR build
    prew_kernel<<<(8192 + 6 * 16384 + 255) / 256, 256, 0, stream>>>(emb_W, W1, W2, wt);
    deg_kernel<<<(NE + 255) / 256, 256, 0, stream>>>(edge, deg);
    bscan_kernel<<<NB, 256, 0, stream>>>(deg, rowptr, bsum);
    off_kernel<<<1, 256, 0, stream>>>(bsum, boff, rowptr);
    addoff_kernel<<<NB, 256, 0, stream>>>(rowptr, boff, cursor);
    fill_kernel<<<(NE + 255) / 256, 256, 0, stream>>>(edge, cursor, adj);

    // embed: y2buf = x @ emb_W + emb_b  (gather-src role)
    gemm_kernel<AD, 0, false><<<gemm_grid, 256, 0, stream>>>(
        x, wt, emb_b, nullptr, nullptr, nullptr, y2buf, nullptr, NN);

    for (int l = 0; l < 3; l++) {
        if (l == 0)
            gather_kernel<false><<<(NN + 15) / 16, 256, 0, stream>>>(
                y2buf, rowptr, adj, stats, g2, be2, eps, l, zbuf);
        else
            gather_kernel<true><<<(NN + 15) / 16, 256, 0, stream>>>(
                y2buf, rowptr, adj, stats + (2 * l - 1) * 256,
                g2 + (l - 1) * HD, be2 + (l - 1) * HD, eps, l, zbuf);
        gemm_kernel<HD, 1, true><<<gemm_grid, 256, 0, stream>>>(
            zbuf, wt + 8192 + (size_t)l * 16384, b1 + l * HD,
            nullptr, nullptr, nullptr, y1buf, stats + (2 * l) * 256, NN);
        gemm_kernel<HD, 2, true><<<gemm_grid, 256, 0, stream>>>(
            y1buf, wt + 8192 + (size_t)(3 + l) * 16384, b2 + l * HD,
            stats + (2 * l) * 256, g1 + l * HD, be1 + l * HD,
            y2buf, stats + (2 * l + 1) * 256, NN);
    }

    starts_kernel<<<(NN + 255) / 256, 256, 0, stream>>>(batch, start);
    pool_kernel<<<NG, 256, 0, stream>>>(y2buf, start, stats + 5 * 256,
                                        g2 + 2 * HD, be2 + 2 * HD, pooled);
    final_kernel<<<NG, 256, 0, stream>>>(pooled, proj_W, proj_b, out);
}